// Round 1
// baseline (409.473 us; speedup 1.0000x reference)
//
#include <hip/hip_runtime.h>

#define NHEAD 8
#define HDIM  32
#define SEQL  1024
#define CDIM  256     // NHEAD * HDIM
#define KC    64      // keys staged per chunk
#define ROWS  256     // q rows per block == blockDim.x

__global__ __launch_bounds__(256) void masked_attn_f32(
    const float* __restrict__ q,
    const float* __restrict__ k,
    const float* __restrict__ v,
    const int*   __restrict__ mask,   // (B, L) 0/1
    const float* __restrict__ bias,   // (B, L, L)
    float*       __restrict__ out)    // (B, 1, L, C) == flat (B, L, C)
{
    __shared__ float sK[KC][HDIM];
    __shared__ float sV[KC][HDIM];
    __shared__ float sMadd[KC];       // 0 or -1e9 per key

    const int tid = threadIdx.x;
    const int blk = blockIdx.x;
    const int bh  = blk >> 2;         // 4 q-chunks per (b,h)
    const int qc  = blk & 3;
    const int b   = bh >> 3;
    const int h   = bh & 7;
    const int qrow = qc * ROWS + tid;

    const float scale = 0.17677669529663687f; // 1/sqrt(32)

    // ---- load this thread's q row (32 contiguous floats) ----
    const float* qp = q + ((size_t)(b * SEQL + qrow) * CDIM + h * HDIM);
    float4 qreg[8];
#pragma unroll
    for (int i = 0; i < 8; ++i) qreg[i] = ((const float4*)qp)[i];

    float4 acc[8];
#pragma unroll
    for (int i = 0; i < 8; ++i) acc[i] = make_float4(0.f, 0.f, 0.f, 0.f);
    float lsum = 0.f;

    const float* biasrow = bias + ((size_t)(b * SEQL) + qrow) * SEQL;

    for (int j0 = 0; j0 < SEQL; j0 += KC) {
        // ---- stage K/V chunk into LDS: 64 rows x 32 floats each ----
        for (int i = tid; i < KC * (HDIM / 4); i += ROWS) {
            int row = i >> 3;         // HDIM/4 == 8 float4 per row
            int c4  = i & 7;
            size_t src = ((size_t)(b * SEQL + j0 + row) * CDIM + h * HDIM + c4 * 4);
            *(float4*)&sK[row][c4 * 4] = *(const float4*)(k + src);
            *(float4*)&sV[row][c4 * 4] = *(const float4*)(v + src);
        }
        if (tid < KC) {
            sMadd[tid] = mask[b * SEQL + j0 + tid] ? 0.f : -1e9f;
        }
        __syncthreads();

        // ---- bias for this chunk (contiguous per thread) ----
        float4 bch[KC / 4];
#pragma unroll
        for (int i = 0; i < KC / 4; ++i)
            bch[i] = ((const float4*)(biasrow + j0))[i];

#pragma unroll 2
        for (int j = 0; j < KC; ++j) {
            const float4* kr = (const float4*)&sK[j][0];
            float p0 = 0.f, p1 = 0.f, p2 = 0.f, p3 = 0.f;
#pragma unroll
            for (int i = 0; i < 8; ++i) {
                float4 kk = kr[i];
                float4 qq = qreg[i];
                p0 = fmaf(qq.x, kk.x, p0);
                p1 = fmaf(qq.y, kk.y, p1);
                p2 = fmaf(qq.z, kk.z, p2);
                p3 = fmaf(qq.w, kk.w, p3);
            }
            float bj = ((const float*)bch)[j];
            float s  = (p0 + p1 + p2 + p3) * scale + bj + sMadd[j];
            float p  = __expf(s);          // masked: exp(-1e9+..) == 0
            lsum += p;
            const float4* vr = (const float4*)&sV[j][0];
#pragma unroll
            for (int i = 0; i < 8; ++i) {
                float4 vv = vr[i];
                acc[i].x = fmaf(p, vv.x, acc[i].x);
                acc[i].y = fmaf(p, vv.y, acc[i].y);
                acc[i].z = fmaf(p, vv.z, acc[i].z);
                acc[i].w = fmaf(p, vv.w, acc[i].w);
            }
        }
        __syncthreads();
    }

    // ---- epilogue: normalize or pass-through value for masked query ----
    const float inv = 1.0f / lsum;
    const int   qactive = mask[b * SEQL + qrow];
    float* op = out + ((size_t)(b * SEQL + qrow) * CDIM + h * HDIM);
    const float* vp = v + ((size_t)(b * SEQL + qrow) * CDIM + h * HDIM);

    if (qactive) {
#pragma unroll
        for (int i = 0; i < 8; ++i) {
            float4 o;
            o.x = acc[i].x * inv;
            o.y = acc[i].y * inv;
            o.z = acc[i].z * inv;
            o.w = acc[i].w * inv;
            ((float4*)op)[i] = o;
        }
    } else {
#pragma unroll
        for (int i = 0; i < 8; ++i)
            ((float4*)op)[i] = ((const float4*)vp)[i];
    }
}

extern "C" void kernel_launch(void* const* d_in, const int* in_sizes, int n_in,
                              void* d_out, int out_size, void* d_ws, size_t ws_size,
                              hipStream_t stream) {
    const float* q    = (const float*)d_in[0];
    const float* k    = (const float*)d_in[1];
    const float* v    = (const float*)d_in[2];
    const int*   mask = (const int*)d_in[3];
    const float* bias = (const float*)d_in[4];
    float* out = (float*)d_out;

    const int B = 8;
    dim3 grid(B * NHEAD * (SEQL / ROWS));  // 256 blocks
    dim3 block(ROWS);                      // 256 threads
    masked_attn_f32<<<grid, block, 0, stream>>>(q, k, v, mask, bias, out);
}

// Round 2
// 138.475 us; speedup vs baseline: 2.9570x; 2.9570x over previous
//
#include <hip/hip_runtime.h>

#define B_    8
#define H_    8
#define L_    1024
#define D_    32
#define C_    256
#define MQ    64      // q rows per block
#define NK    64      // keys per chunk
#define KSTR  48      // sQ/sK row stride in bf16 elems (32 + 16 pad; keeps 16B align, 24-bank shift)
#define VSTR  72      // sVt row stride (64 + 8 pad; 16B align)
#define PSTR  72      // sP row stride

typedef __attribute__((ext_vector_type(8))) short bf16x8;
typedef __attribute__((ext_vector_type(4))) float f32x4;

__device__ inline unsigned short f2bf(float f) {   // RNE f32 -> bf16
    union { float f; unsigned int u; } x; x.f = f;
    return (unsigned short)((x.u + 0x7fffu + ((x.u >> 16) & 1u)) >> 16);
}

__global__ __launch_bounds__(256) void masked_attn_mfma(
    const float* __restrict__ q,
    const float* __restrict__ k,
    const float* __restrict__ v,
    const int*   __restrict__ mask,   // (B, L) 0/1
    const float* __restrict__ bias,   // (B, L, L)
    float*       __restrict__ out)    // flat (B, L, C)
{
    __shared__ __align__(16) unsigned short sQ[MQ][KSTR];
    __shared__ __align__(16) unsigned short sK[NK][KSTR];
    __shared__ __align__(16) unsigned short sVt[D_][VSTR];   // [dim][key]
    __shared__ __align__(16) unsigned short sP[4][16][PSTR]; // per-wave strip
    __shared__ float sMadd[NK];

    const int tid  = threadIdx.x;
    const int wv   = tid >> 6;
    const int ln   = tid & 63;
    const int l16  = ln & 15;
    const int quad = ln >> 4;

    const int blk = blockIdx.x;
    const int h   = blk & 7;          // head fastest: same (b,qt) co-resident -> bias L2/L3 reuse
    const int qt  = (blk >> 3) & 15;
    const int b   = blk >> 7;
    const int q0  = qt * MQ;

    const float scale = 0.17677669529663687f; // 1/sqrt(32)

    // ---- stage Q tile (64x32 f32 -> bf16), thread t: row=t>>2, d0=(t&3)*8 ----
    {
        const int row = tid >> 2, d0 = (tid & 3) * 8;
        const float* src = q + ((size_t)(b * L_ + q0 + row) * C_ + h * D_ + d0);
        float4 a = ((const float4*)src)[0];
        float4 c = ((const float4*)src)[1];
        __align__(16) unsigned short t8[8] = {
            f2bf(a.x), f2bf(a.y), f2bf(a.z), f2bf(a.w),
            f2bf(c.x), f2bf(c.y), f2bf(c.z), f2bf(c.w)};
        *(int4*)&sQ[row][d0] = *(const int4*)t8;
    }
    __syncthreads();

    // A-frag of Q: m = l16 (within this wave's 16-row strip), k = quad*8..+7 — loop-invariant
    const bf16x8 qfrag = *(const bf16x8*)&sQ[wv * 16 + l16][quad * 8];

    f32x4 Oacc[2] = {{0.f,0.f,0.f,0.f},{0.f,0.f,0.f,0.f}};
    float lsum[4] = {0.f, 0.f, 0.f, 0.f};

    for (int j0 = 0; j0 < L_; j0 += NK) {
        __syncthreads();   // previous chunk's K/V reads complete
        {
            const int row = tid >> 2, d0 = (tid & 3) * 8;
            const size_t src = (size_t)(b * L_ + j0 + row) * C_ + h * D_ + d0;
            float4 ka = ((const float4*)(k + src))[0];
            float4 kb = ((const float4*)(k + src))[1];
            __align__(16) unsigned short t8[8] = {
                f2bf(ka.x), f2bf(ka.y), f2bf(ka.z), f2bf(ka.w),
                f2bf(kb.x), f2bf(kb.y), f2bf(kb.z), f2bf(kb.w)};
            *(int4*)&sK[row][d0] = *(const int4*)t8;

            float4 va = ((const float4*)(v + src))[0];
            float4 vb = ((const float4*)(v + src))[1];
            sVt[d0 + 0][row] = f2bf(va.x);
            sVt[d0 + 1][row] = f2bf(va.y);
            sVt[d0 + 2][row] = f2bf(va.z);
            sVt[d0 + 3][row] = f2bf(va.w);
            sVt[d0 + 4][row] = f2bf(vb.x);
            sVt[d0 + 5][row] = f2bf(vb.y);
            sVt[d0 + 6][row] = f2bf(vb.z);
            sVt[d0 + 7][row] = f2bf(vb.w);
            if (tid < NK) sMadd[tid] = mask[b * L_ + j0 + tid] ? 0.f : -1e9f;
        }
        __syncthreads();

        // ---- QK^T: S[q][key], 4 n-tiles of 16 keys ----
        bf16x8 kf[4];
#pragma unroll
        for (int nt = 0; nt < 4; ++nt)
            kf[nt] = *(const bf16x8*)&sK[nt * 16 + l16][quad * 8];

        f32x4 S[4];
#pragma unroll
        for (int nt = 0; nt < 4; ++nt)
            S[nt] = __builtin_amdgcn_mfma_f32_16x16x32_bf16(
                qfrag, kf[nt], (f32x4){0.f,0.f,0.f,0.f}, 0, 0, 0);

        // ---- bias + mask + exp (fp32), C-layout: col=l16(+16*nt), row=quad*4+reg ----
        float psum[4] = {0.f, 0.f, 0.f, 0.f};
        const size_t brow0 = (size_t)(b * L_ + q0 + wv * 16 + quad * 4) * L_ + j0;
#pragma unroll
        for (int nt = 0; nt < 4; ++nt) {
            const float madd = sMadd[nt * 16 + l16];
#pragma unroll
            for (int r = 0; r < 4; ++r) {
                float s = S[nt][r] * scale + bias[brow0 + (size_t)r * L_ + nt * 16 + l16] + madd;
                float p = __expf(s);   // masked key: exp(-1e9) == 0 exactly
                psum[r] += p;
                S[nt][r] = p;
            }
        }

        // ---- P -> bf16 -> this wave's LDS strip (A-layout source) ----
#pragma unroll
        for (int nt = 0; nt < 4; ++nt)
#pragma unroll
            for (int r = 0; r < 4; ++r)
                sP[wv][quad * 4 + r][nt * 16 + l16] = f2bf(S[nt][r]);

        // ---- per-row sum: butterfly over the 16 lanes of this quad ----
#pragma unroll
        for (int r = 0; r < 4; ++r) {
            float t = psum[r];
            t += __shfl_xor(t, 1);
            t += __shfl_xor(t, 2);
            t += __shfl_xor(t, 4);
            t += __shfl_xor(t, 8);
            lsum[r] += t;
        }

        // ---- PV: O += P * V  (A-frag rows are this wave's own strip; no barrier) ----
#pragma unroll
        for (int s = 0; s < 2; ++s) {
            bf16x8 pf = *(const bf16x8*)&sP[wv][l16][s * 32 + quad * 8];
#pragma unroll
            for (int nt = 0; nt < 2; ++nt) {
                bf16x8 vf = *(const bf16x8*)&sVt[nt * 16 + l16][s * 32 + quad * 8];
                Oacc[nt] = __builtin_amdgcn_mfma_f32_16x16x32_bf16(pf, vf, Oacc[nt], 0, 0, 0);
            }
        }
    }

    // ---- epilogue: normalize, or pass value through for inactive query rows ----
#pragma unroll
    for (int r = 0; r < 4; ++r) {
        const int qg = q0 + wv * 16 + quad * 4 + r;
        const int active = mask[b * L_ + qg];
        const size_t obase = (size_t)(b * L_ + qg) * C_ + h * D_;
        const float inv = 1.f / lsum[r];
#pragma unroll
        for (int nt = 0; nt < 2; ++nt) {
            float val;
            if (active) val = Oacc[nt][r] * inv;
            else        val = v[obase + nt * 16 + l16];
            out[obase + nt * 16 + l16] = val;
        }
    }
}

extern "C" void kernel_launch(void* const* d_in, const int* in_sizes, int n_in,
                              void* d_out, int out_size, void* d_ws, size_t ws_size,
                              hipStream_t stream) {
    const float* q    = (const float*)d_in[0];
    const float* k    = (const float*)d_in[1];
    const float* v    = (const float*)d_in[2];
    const int*   mask = (const int*)d_in[3];
    const float* bias = (const float*)d_in[4];
    float* out = (float*)d_out;

    dim3 grid(B_ * H_ * (L_ / MQ));   // 1024 blocks
    dim3 block(256);                  // 4 waves
    masked_attn_mfma<<<grid, block, 0, stream>>>(q, k, v, mask, bias, out);
}